// Round 12
// baseline (79.172 us; speedup 1.0000x reference)
//
#include <hip/hip_runtime.h>
#include <hip/hip_bf16.h>

// B=8, N=256, D=128, H=256, K=128
// out[b,i,j,k] = exp(-(v - means[k])^2 * |temps[k]|)
//   v    = mul * x[b,i,j] + bias
//   mul  = (sum_h relu(hi[b,i,h]+hj[b,j,h]+b1[h]) * W2[h,0] + b2[0]) * 0.0625
//   bias = (                 "                    * W2[h,1] + b2[1]) * 0.0625

#define NB 8
#define NN 256
#define ND 128
#define NH 256
#define NK 128
#define IG 8    // i-rows per block
#define JT 64   // j-tile per block (= wave width)

typedef float f32x4 __attribute__((ext_vector_type(4)));
typedef float f32x2 __attribute__((ext_vector_type(2)));

// ---------------- Kernel A: hi[bi][h] and hjbT[b][h][j] = hj + b1 ----------------
__global__ __launch_bounds__(256) void precompute_hij(
    const float* __restrict__ atom, const float* __restrict__ W1,
    const float* __restrict__ b1,
    float* __restrict__ hi, float* __restrict__ hjbT) {
  const int h = threadIdx.x;
  const int base = blockIdx.x * 8;
  const int b  = base >> 8;
  const int j0 = base & 255;
  __shared__ float a[8][ND];
  for (int t = threadIdx.x; t < 8 * ND; t += 256) {
    a[t >> 7][t & 127] = atom[(size_t)base * ND + t];
  }
  __syncthreads();
  float acc0[8], acc1[8];
  const float bv = b1[h];
#pragma unroll
  for (int r = 0; r < 8; ++r) { acc0[r] = 0.f; acc1[r] = bv; }
  for (int d = 0; d < ND; ++d) {
    const float w0 = W1[d * NH + h];
    const float w1 = W1[(ND + d) * NH + h];
#pragma unroll
    for (int r = 0; r < 8; ++r) {
      acc0[r] = fmaf(a[r][d], w0, acc0[r]);
      acc1[r] = fmaf(a[r][d], w1, acc1[r]);
    }
  }
#pragma unroll
  for (int r = 0; r < 8; ++r) {
    hi[(size_t)(base + r) * NH + h] = acc0[r];
    hjbT[((size_t)b * NH + h) * NN + (j0 + r)] = acc1[r];
  }
}

// ---------------- Fused kernel: register-resident hj panel slice ----------------
// grid = 8b x 4jt x 32ig = 1024 blocks, 256 threads (4 waves).
// Wave wv owns h in [64wv, 64wv+64); lane = j - j0. hj slice: 64 VGPRs/lane,
// loaded once. hi/W2 are uniform s_loads. Per i: dot -> 1 barrier -> v (all
// waves) -> RBF + coalesced float4 stores (v via __shfl). Stores drain under
// the next i's dot; 4 blocks/CU interleave micro-phases.
__global__ __launch_bounds__(256) void edge_rbf(
    const float* __restrict__ x,
    const float* __restrict__ hi, const float* __restrict__ hjbT,
    const float* __restrict__ W2, const float* __restrict__ b2,
    const float* __restrict__ means, const float* __restrict__ temps,
    float* __restrict__ out) {
  const int b  = blockIdx.x & 7;
  const int jt = (blockIdx.x >> 3) & 3;
  const int ig = blockIdx.x >> 5;                 // 0..31
  const int i0 = ig * IG;
  const int j0 = jt * JT;
  const int lane = threadIdx.x & 63;
  const int wv = __builtin_amdgcn_readfirstlane((int)(threadIdx.x >> 6)); // SGPR 0..3
  const int h0 = wv * 64;

  __shared__ f32x2 part[2][4][64];                // 4 KB, double-buffered

  // ---- Load hj panel slice into registers (once) ----
  float hj[64];
  {
    const float* __restrict__ hjb = hjbT + ((size_t)b * NH + h0) * NN + j0 + lane;
#pragma unroll
    for (int hh = 0; hh < 64; ++hh) hj[hh] = hjb[(size_t)hh * NN];
  }

  const float* __restrict__ w2s = W2 + 2 * h0;    // uniform -> s_loads
  const float* hib  = hi + ((size_t)(b * NN + i0)) * NH + h0;  // uniform
  const float* xrow = x + ((size_t)(b * NN + i0)) * NN + j0;

  const float scale = 0.0625f;                    // 1/sqrt(2*128)
  const float b20 = b2[0], b21 = b2[1];

  // store-phase constants: thread -> k-quad k0, j-offset jj
  const int k0 = (threadIdx.x & 31) * 4;
  const int jj = threadIdx.x >> 5;                // 0..7
  const float LOG2E = 1.44269504088896340736f;
  const f32x4 mv = *reinterpret_cast<const f32x4*>(means + k0);
  const f32x4 tv = *reinterpret_cast<const f32x4*>(temps + k0);
  const float t0 = -fabsf(tv.x) * LOG2E;
  const float t1 = -fabsf(tv.y) * LOG2E;
  const float t2 = -fabsf(tv.z) * LOG2E;
  const float t3 = -fabsf(tv.w) * LOG2E;

  float* outb = out + (((size_t)(b * NN + i0)) * NN + j0) * NK + k0;

  for (int i = 0; i < IG; ++i) {
    // ---- dot over wave's 64 h (hj in regs, hi/W2 scalar) ----
    float s0 = 0.f, s1 = 0.f;
#pragma unroll
    for (int hh = 0; hh < 64; ++hh) {
      const float a = fmaxf(hib[hh] + hj[hh], 0.f);
      s0 = fmaf(a, w2s[2 * hh],     s0);
      s1 = fmaf(a, w2s[2 * hh + 1], s1);
    }
    part[i & 1][wv][lane] = f32x2{s0, s1};
    __syncthreads();   // also drains previous i's stores (overlapped with dot)

    // ---- v per lane (every wave has all 64 j) ----
    const f32x2 p0 = part[i & 1][0][lane];
    const f32x2 p1 = part[i & 1][1][lane];
    const f32x2 p2 = part[i & 1][2][lane];
    const f32x2 p3 = part[i & 1][3][lane];
    const float mul  = ((p0.x + p1.x + p2.x + p3.x) + b20) * scale;
    const float bias = ((p0.y + p1.y + p2.y + p3.y) + b21) * scale;
    const float vv = fmaf(mul, xrow[lane], bias);

    // ---- RBF + stores: 8 passes, j = j0 + jj + 8p ----
    float* __restrict__ oi = outb + (size_t)i * NN * NK;
#pragma unroll
    for (int p = 0; p < 8; ++p) {
      const float vj = __shfl(vv, jj + 8 * p, 64);
      const float d0 = vj - mv.x;
      const float d1 = vj - mv.y;
      const float d2 = vj - mv.z;
      const float d3 = vj - mv.w;
      f32x4 e;
      e.x = __builtin_amdgcn_exp2f(d0 * d0 * t0);
      e.y = __builtin_amdgcn_exp2f(d1 * d1 * t1);
      e.z = __builtin_amdgcn_exp2f(d2 * d2 * t2);
      e.w = __builtin_amdgcn_exp2f(d3 * d3 * t3);
      *reinterpret_cast<f32x4*>(oi + (size_t)(jj + 8 * p) * NK) = e;
    }
    hib  += NH;
    xrow += NN;
  }
}

extern "C" void kernel_launch(void* const* d_in, const int* in_sizes, int n_in,
                              void* d_out, int out_size, void* d_ws, size_t ws_size,
                              hipStream_t stream) {
  const float* x     = (const float*)d_in[0];
  const float* atom  = (const float*)d_in[1];
  const float* W1    = (const float*)d_in[2];
  const float* b1    = (const float*)d_in[3];
  const float* W2    = (const float*)d_in[4];
  const float* b2    = (const float*)d_in[5];
  const float* means = (const float*)d_in[6];
  const float* temps = (const float*)d_in[7];
  float* out = (float*)d_out;

  float* hi   = (float*)d_ws;                        // 2 MB: [B*N][H]
  float* hjbT = hi + (size_t)NB * NN * NH;           // 2 MB: [B][H][N]

  precompute_hij<<<NB * NN / 8, 256, 0, stream>>>(atom, W1, b1, hi, hjbT);
  edge_rbf<<<NB * (NN / JT) * (NN / IG), 256, 0, stream>>>(x, hi, hjbT, W2, b2, means, temps, out);
}